// Round 3
// baseline (48.762 us; speedup 1.0000x reference)
//
#include <hip/hip_runtime.h>

#define BT 64
#define NTHREADS 256

typedef __attribute__((ext_vector_type(8))) __bf16 bf16x8;
typedef __attribute__((ext_vector_type(4))) float f32x4;

__device__ __forceinline__ __bf16 f2bf(float f) { return (__bf16)f; }
__device__ __forceinline__ f32x4 ld4(const float* p) { return *(const f32x4*)p; }

// One-time: convert w1 (64x192) and w2 (96x64) f32 -> bf16 into ws.
__global__ void prep_weights(const float* __restrict__ w1, const float* __restrict__ w2,
                             __bf16* __restrict__ wbf) {
    const int i = blockIdx.x * 256 + threadIdx.x;
    if (i < 12288)       wbf[i] = f2bf(w1[i]);
    else if (i < 18432)  wbf[i] = f2bf(w2[i - 12288]);
}

__global__ __launch_bounds__(NTHREADS, 4)
void ncf_fused(const int* __restrict__ user_ids, const int* __restrict__ movie_ids,
               const int* __restrict__ genre_ids, const int* __restrict__ offsets,
               const float* __restrict__ user_mem_w, const float* __restrict__ movie_mem_w,
               const float* __restrict__ ue_gmf, const float* __restrict__ me_gmf,
               const float* __restrict__ ge_gmf,
               const float* __restrict__ ue_mlp, const float* __restrict__ me_mlp,
               const float* __restrict__ ge_mlp,
               const float* __restrict__ b1, const float* __restrict__ b2,
               const float* __restrict__ w_out, const float* __restrict__ b_out,
               const __bf16* __restrict__ wbf,
               float* __restrict__ out, int Btot, int totG)
{
    __shared__ __bf16 Hs[BT * 72];   // H [64][64+8] bf16

    const int tid  = threadIdx.x;
    const int lane = tid & 63;
    const int wid  = tid >> 6;       // 4 waves, 16 elements each
    const int lr   = lane & 15;      // element-row within wave tile
    const int lg   = lane >> 4;      // chunk group (0..3)
    const int e0   = blockIdx.x * BT;

    const int erow = wid * 16 + lr;
    const int gidx = min(e0 + erow, Btot - 1);
    const int u    = user_ids[gidx];
    const int mv   = movie_ids[gidx];
    const int gs   = offsets[gidx];
    const int gend = (gidx + 1 < Btot) ? offsets[gidx + 1] : totG;
    const int cnt  = gend - gs;
    const float inv = 1.0f / (float)(cnt > 0 ? cnt : 1);

    // ===== Batch 1: issue all GMF gathers (10 x 16B, independent) =====
    const float* ugp = ue_gmf + (size_t)u * 96 + 4 * lg;
    f32x4 ug0 = ld4(ugp +  0), ug1 = ld4(ugp + 16), ug2 = ld4(ugp + 32),
          ug3 = ld4(ugp + 48), ug4 = ld4(ugp + 64), ug5 = ld4(ugp + 80);
    const float* mgp = me_gmf + (size_t)mv * 64 + 4 * lg;
    f32x4 mg0 = ld4(mgp + 0), mg1 = ld4(mgp + 16), mg2 = ld4(mgp + 32), mg3 = ld4(mgp + 48);
    const float um = user_mem_w[u];
    const float mm = movie_mem_w[mv];

    // ===== Genre pass (L1-resident tables), overlaps batch-1 latency =====
    // gg0/gg1: ge_gmf[g][4lg], [16+4lg];  gm0/gm1: ge_mlp[g][8lg .. +7]
    f32x4 gg0 = {0.f,0.f,0.f,0.f}, gg1 = {0.f,0.f,0.f,0.f};
    f32x4 gm0 = {0.f,0.f,0.f,0.f}, gm1 = {0.f,0.f,0.f,0.f};
    for (int i = gs; i < gend; ++i) {
        const int g = genre_ids[i];
        const float* pg = ge_gmf + (size_t)g * 32 + 4 * lg;
        gg0 += ld4(pg);
        gg1 += ld4(pg + 16);
        const float* pm = ge_mlp + (size_t)g * 32 + 8 * lg;
        gm0 += ld4(pm);
        gm1 += ld4(pm + 4);
    }

    // ===== Batch 2: issue all MLP-input gathers (10 x 16B) =====
    const float* up = ue_mlp + (size_t)u * 96 + lg * 8;
    f32x4 ua0 = ld4(up +  0), ub0 = ld4(up +  4),
          ua1 = ld4(up + 32), ub1 = ld4(up + 36),
          ua2 = ld4(up + 64), ub2 = ld4(up + 68);
    const float* mp = me_mlp + (size_t)mv * 64 + lg * 8;
    f32x4 ma0 = ld4(mp +  0), mb0 = ld4(mp +  4),
          ma1 = ld4(mp + 32), mb1 = ld4(mp + 36);

    // ===== GMF dot (consumes batch 1; batch 2 still in flight) =====
    float pval;
    {
        const float* wop = w_out + 4 * lg;
        f32x4 wo0 = ld4(wop), wo1 = ld4(wop + 16), wo2 = ld4(wop + 32),
              wo3 = ld4(wop + 48), wo4 = ld4(wop + 64), wo5 = ld4(wop + 80);
        float s = 0.f;
        #pragma unroll
        for (int q = 0; q < 4; ++q) {
            s += ug0[q]*mg0[q]*wo0[q] + ug1[q]*mg1[q]*wo1[q]
               + ug2[q]*mg2[q]*wo2[q] + ug3[q]*mg3[q]*wo3[q];
            s += ug4[q]*(gg0[q]*inv)*wo4[q] + ug5[q]*(gg1[q]*inv)*wo5[q];
        }
        if (lg == 0) s += um + mm + b_out[0];
        s += __shfl_xor(s, 16);
        s += __shfl_xor(s, 32);
        pval = s;
    }

    // ===== Convert batch 2 into A-fragments =====
    bf16x8 fr[6];
    #pragma unroll
    for (int kt = 0; kt < 6; ++kt) {
        f32x4 a, b;
        if      (kt == 0) { a = ua0; b = ub0; }
        else if (kt == 1) { a = ua1; b = ub1; }
        else if (kt == 2) { a = ua2; b = ub2; }
        else if (kt == 3) { a = ma0; b = mb0; }
        else if (kt == 4) { a = ma1; b = mb1; }
        else              { a = gm0 * inv; b = gm1 * inv; }
        bf16x8 t;
        t[0]=f2bf(a[0]); t[1]=f2bf(a[1]); t[2]=f2bf(a[2]); t[3]=f2bf(a[3]);
        t[4]=f2bf(b[0]); t[5]=f2bf(b[1]); t[6]=f2bf(b[2]); t[7]=f2bf(b[3]);
        fr[kt] = t;
    }

    // ===== GEMM1: X[64x192] @ W1^T -> H[64x64] =====
    const __bf16* w1bf = wbf;
    f32x4 acc1[4] = {};
    #pragma unroll
    for (int kt = 0; kt < 6; ++kt) {
        #pragma unroll
        for (int nt = 0; nt < 4; ++nt) {
            bf16x8 bw = *(const bf16x8*)(w1bf + (size_t)(nt * 16 + lr) * 192 + kt * 32 + lg * 8);
            acc1[nt] = __builtin_amdgcn_mfma_f32_16x16x32_bf16(fr[kt], bw, acc1[nt], 0, 0, 0);
        }
    }
    #pragma unroll
    for (int nt = 0; nt < 4; ++nt) {
        const float bv = b1[nt * 16 + lr];
        #pragma unroll
        for (int r = 0; r < 4; ++r) {
            float v = acc1[nt][r] + bv;
            v = v > 0.f ? v : 0.f;
            Hs[(wid * 16 + lg * 4 + r) * 72 + nt * 16 + lr] = f2bf(v);
        }
    }
    __syncthreads();

    // ===== GEMM2: H[64x64] @ W2^T -> [64x96], fused epilogue =====
    const __bf16* w2bf = wbf + 12288;
    f32x4 acc2[6] = {};
    #pragma unroll
    for (int kt = 0; kt < 2; ++kt) {
        bf16x8 av = *(const bf16x8*)&Hs[(wid * 16 + lr) * 72 + kt * 32 + lg * 8];
        #pragma unroll
        for (int nt = 0; nt < 6; ++nt) {
            bf16x8 bw = *(const bf16x8*)(w2bf + (size_t)(nt * 16 + lr) * 64 + kt * 32 + lg * 8);
            acc2[nt] = __builtin_amdgcn_mfma_f32_16x16x32_bf16(av, bw, acc2[nt], 0, 0, 0);
        }
    }

    float s0 = 0.f, s1 = 0.f, s2 = 0.f, s3 = 0.f;
    #pragma unroll
    for (int nt = 0; nt < 6; ++nt) {
        const int col = nt * 16 + lr;
        const float b2v = b2[col];
        const float wo  = w_out[96 + col];
        float v;
        v = acc2[nt][0] + b2v; v = v > 0.f ? v : 0.f; s0 += v * wo;
        v = acc2[nt][1] + b2v; v = v > 0.f ? v : 0.f; s1 += v * wo;
        v = acc2[nt][2] + b2v; v = v > 0.f ? v : 0.f; s2 += v * wo;
        v = acc2[nt][3] + b2v; v = v > 0.f ? v : 0.f; s3 += v * wo;
    }
    #pragma unroll
    for (int mask = 1; mask <= 8; mask <<= 1) {
        s0 += __shfl_xor(s0, mask);
        s1 += __shfl_xor(s1, mask);
        s2 += __shfl_xor(s2, mask);
        s3 += __shfl_xor(s3, mask);
    }
    const float p0 = __shfl(pval, lg * 4 + 0);
    const float p1 = __shfl(pval, lg * 4 + 1);
    const float p2 = __shfl(pval, lg * 4 + 2);
    const float p3 = __shfl(pval, lg * 4 + 3);

    if (lr == 0) {
        const int rowb = e0 + wid * 16 + lg * 4;
        if (rowb + 0 < Btot) out[rowb + 0] = p0 + s0;
        if (rowb + 1 < Btot) out[rowb + 1] = p1 + s1;
        if (rowb + 2 < Btot) out[rowb + 2] = p2 + s2;
        if (rowb + 3 < Btot) out[rowb + 3] = p3 + s3;
    }
}

extern "C" void kernel_launch(void* const* d_in, const int* in_sizes, int n_in,
                              void* d_out, int out_size, void* d_ws, size_t ws_size,
                              hipStream_t stream) {
    const int*   user_ids    = (const int*)d_in[0];
    const int*   movie_ids   = (const int*)d_in[1];
    const int*   genre_ids   = (const int*)d_in[2];
    const int*   offsets     = (const int*)d_in[3];
    const float* user_mem_w  = (const float*)d_in[4];
    const float* movie_mem_w = (const float*)d_in[5];
    const float* ue_gmf      = (const float*)d_in[6];
    const float* me_gmf      = (const float*)d_in[7];
    const float* ge_gmf      = (const float*)d_in[8];
    const float* ue_mlp      = (const float*)d_in[9];
    const float* me_mlp      = (const float*)d_in[10];
    const float* ge_mlp      = (const float*)d_in[11];
    const float* w1          = (const float*)d_in[12];
    const float* b1          = (const float*)d_in[13];
    const float* w2          = (const float*)d_in[14];
    const float* b2          = (const float*)d_in[15];
    const float* w_out       = (const float*)d_in[16];
    const float* b_out       = (const float*)d_in[17];

    const int Btot = in_sizes[0];
    const int totG = in_sizes[2];

    __bf16* wbf = (__bf16*)d_ws;
    prep_weights<<<72, 256, 0, stream>>>(w1, w2, wbf);

    const int grid = (Btot + BT - 1) / BT;
    ncf_fused<<<grid, NTHREADS, 0, stream>>>(
        user_ids, movie_ids, genre_ids, offsets,
        user_mem_w, movie_mem_w,
        ue_gmf, me_gmf, ge_gmf,
        ue_mlp, me_mlp, ge_mlp,
        b1, b2, w_out, b_out,
        wbf, (float*)d_out, Btot, totG);
}